// Round 5
// baseline (2466.425 us; speedup 1.0000x reference)
//
#include <hip/hip_runtime.h>
#include <hip/hip_bf16.h>

// GRU T=1024 B=64 I=256 H=256.
// d_in order: X, W_fx, W_fg, b_fg, W_ix, W_ig, b_ig, W_ux, W_ug, b_ug (all f32)
// d_out: outs [T,B,H] f32 then h_last [B,H] f32.

typedef _Float16 h2 __attribute__((ext_vector_type(2)));
typedef short bf16x8 __attribute__((ext_vector_type(8)));
typedef float f32x4 __attribute__((ext_vector_type(4)));
typedef unsigned short u16;
typedef unsigned int u32;

union UQ { uint4 u; h2 h[4]; };

#if __has_builtin(__builtin_amdgcn_fdot2)
#define FDOT2(a, b, c) __builtin_amdgcn_fdot2((a), (b), (c), false)
#else
static __device__ inline float FDOT2(h2 a, h2 b, float c) {
    return c + (float)a[0] * (float)b[0] + (float)a[1] * (float)b[1];
}
#endif

__device__ inline u16 f2bf(float f) {
    u32 u = __float_as_uint(f);
    u = (u + 0x7FFF + ((u >> 16) & 1)) >> 16;   // RNE
    return (u16)u;
}

// Opaque pin: keeps the loaded weight values' origin invisible so LLVM cannot
// re-sink the loads into the loop. With demand <= 128 VGPR (the 4-wave/SIMD
// budget) the allocator has no spill incentive either.
__device__ inline void pin(h2& x) { asm volatile("" : "+v"(x)); }

// Raw workgroup barrier: LDS-visibility only, no vmcnt drain (global
// loads/stores here are thread-private and may stay in flight).
__device__ inline void wg_barrier() {
    asm volatile("s_waitcnt lgkmcnt(0)" ::: "memory");
    __builtin_amdgcn_s_barrier();
    asm volatile("" ::: "memory");
}

// ---------------- prep: WcatT [768][256] bf16: WcatT[g*256+j][k] = Wgx[k][j]
__global__ void prep_wcat(const float* __restrict__ Wfx, const float* __restrict__ Wix,
                          const float* __restrict__ Wux, u16* __restrict__ WcatT) {
    int n = blockIdx.x;            // 0..767
    int k = threadIdx.x;           // 0..255
    int g = n >> 8, j = n & 255;
    const float* W = (g == 0) ? Wfx : (g == 1) ? Wix : Wux;
    WcatT[(size_t)n * 256 + k] = f2bf(W[(size_t)k * 256 + j]);
}

// ---------------- prep: WT f16 [3][256][256]: WT[g][j][i] = Wg[i][j] + bg[j]
__global__ void prep_wrec(const float* __restrict__ Wfg, const float* __restrict__ bfg,
                          const float* __restrict__ Wig, const float* __restrict__ big,
                          const float* __restrict__ Wug, const float* __restrict__ bug,
                          _Float16* __restrict__ WT) {
    int n = blockIdx.x;            // 0..767
    int i = threadIdx.x;           // 0..255
    int g = n >> 8, j = n & 255;
    const float* W = (g == 0) ? Wfg : (g == 1) ? Wig : Wug;
    const float* bv = (g == 0) ? bfg : (g == 1) ? big : bug;
    WT[(size_t)n * 256 + i] = (_Float16)(W[(size_t)i * 256 + j] + bv[j]);
}

// ---------------- projection GEMM: proj[65536][768] f16 = X[65536][256] @ Wcat[256][768]
__global__ __launch_bounds__(256) void proj_gemm(const float* __restrict__ X,
                                                 const u16* __restrict__ WT, // WcatT [768][256]
                                                 _Float16* __restrict__ proj) {
    __shared__ u16 shA[128][32];
    __shared__ u16 shB[128][32];
    __shared__ _Float16 shC[128][128];

    int tid = threadIdx.x;
    int bn = blockIdx.x % 6, bm = blockIdx.x / 6;
    int lane = tid & 63, wv = tid >> 6;
    int wr = wv >> 1, wc = wv & 1;

    f32x4 acc[4][4];
#pragma unroll
    for (int m = 0; m < 4; m++)
#pragma unroll
        for (int n = 0; n < 4; n++) acc[m][n] = (f32x4){0.f, 0.f, 0.f, 0.f};

    for (int kt = 0; kt < 8; ++kt) {
#pragma unroll
        for (int q = 0; q < 4; ++q) {
            int g = tid + 256 * q;
            int r = g >> 3, c4 = g & 7;
            const float4 v = *(const float4*)(X + (size_t)(bm * 128 + r) * 256 + kt * 32 + c4 * 4);
            ushort4 o;
            o.x = f2bf(v.x); o.y = f2bf(v.y); o.z = f2bf(v.z); o.w = f2bf(v.w);
            *(ushort4*)&shA[r][c4 * 4] = o;
        }
#pragma unroll
        for (int q = 0; q < 2; ++q) {
            int g = tid + 256 * q;
            int r = g >> 2, c8 = g & 3;
            uint4 v = *(const uint4*)(WT + (size_t)(bn * 128 + r) * 256 + kt * 32 + c8 * 8);
            *(uint4*)&shB[r][c8 * 8] = v;
        }
        __syncthreads();

        bf16x8 af[4], bfr[4];
#pragma unroll
        for (int m = 0; m < 4; m++)
            af[m] = *(const bf16x8*)&shA[wr * 64 + m * 16 + (lane & 15)][(lane >> 4) * 8];
#pragma unroll
        for (int n = 0; n < 4; n++)
            bfr[n] = *(const bf16x8*)&shB[wc * 64 + n * 16 + (lane & 15)][(lane >> 4) * 8];
#pragma unroll
        for (int m = 0; m < 4; m++)
#pragma unroll
            for (int n = 0; n < 4; n++)
                acc[m][n] = __builtin_amdgcn_mfma_f32_16x16x32_bf16(af[m], bfr[n], acc[m][n], 0, 0, 0);
        __syncthreads();
    }

#pragma unroll
    for (int m = 0; m < 4; m++)
#pragma unroll
        for (int n = 0; n < 4; n++)
#pragma unroll
            for (int r = 0; r < 4; r++) {
                int row = wr * 64 + m * 16 + (lane >> 4) * 4 + r;
                int col = wc * 64 + n * 16 + (lane & 15);
                shC[row][col] = (_Float16)acc[m][n][r];
            }
    __syncthreads();
    {
        int row = tid >> 1, hf = tid & 1;
        size_t gbase = (size_t)(bm * 128 + row) * 768 + bn * 128 + hf * 64;
        const uint4* src = (const uint4*)&shC[row][hf * 64];
        uint4* dst = (uint4*)(proj + gbase);
#pragma unroll
        for (int q = 0; q < 8; q++) dst[q] = src[q];
    }
}

// ---------------- recurrence: 64 WGs (one per batch), 1024 threads (16 waves,
// 4 waves/SIMD). Thread (p = tid>>8, j = tid&255): 4 threads per column.
// Phase A: p0 -> f-gate over h[0:128], p1 -> f over h[128:256],
//          p2 -> i over h[0:128],      p3 -> i over h[128:256]   (64 h2 each)
// Phase B: p  -> u-gate over rh[p*64:(p+1)*64]                    (32 h2 each)
// Per-thread weights = 96 h2 regs + ~22 misc < 128 VGPR = the allocator's
// natural 4-wave/SIMD budget -> register-resident WITHOUT fighting the RA
// (rounds 2-4: any design needing >128 VGPRs at >=8 waves/WG got spilled).
__global__ __launch_bounds__(1024) void gru_rec(const _Float16* __restrict__ proj,
                                                const _Float16* __restrict__ WT,
                                                float* __restrict__ out) {
    int b = blockIdx.x;
    int tid = threadIdx.x;
    int j = tid & 255;
    int p = tid >> 8;          // wave-uniform (4 waves per p)

    __shared__ __align__(16) _Float16 sh_h[256];   // f16 h (for dots)
    __shared__ __align__(16) _Float16 sh_rh[256];  // f16 reset*h
    __shared__ __align__(16) float sh_hf[256];     // f32 h (exact state)
    __shared__ __align__(16) float sh_pa[1024];    // partial sums (A and B phases)

    int g = p >> 1, half = p & 1;

    // phase-A weights: WT[g][j][half*128 .. +128] -> 64 h2
    h2 wa[64];
    {
        const uint4* p4 = (const uint4*)(WT + (size_t)g * 65536 + (size_t)j * 256 + half * 128);
#pragma unroll
        for (int m = 0; m < 16; m++) {
            UQ a; a.u = p4[m];
            wa[4 * m] = a.h[0]; wa[4 * m + 1] = a.h[1];
            wa[4 * m + 2] = a.h[2]; wa[4 * m + 3] = a.h[3];
        }
    }
    // phase-B weights: WT[2][j][p*64 .. +64] -> 32 h2
    h2 wu[32];
    {
        const uint4* p4 = (const uint4*)(WT + 131072 + (size_t)j * 256 + p * 64);
#pragma unroll
        for (int m = 0; m < 8; m++) {
            UQ a; a.u = p4[m];
            wu[4 * m] = a.h[0]; wu[4 * m + 1] = a.h[1];
            wu[4 * m + 2] = a.h[2]; wu[4 * m + 3] = a.h[3];
        }
    }
#pragma unroll
    for (int m = 0; m < 64; m++) pin(wa[m]);
#pragma unroll
    for (int m = 0; m < 32; m++) pin(wu[m]);

    if (p == 0) { sh_h[j] = (_Float16)0.f; sh_hf[j] = 0.f; }
    __syncthreads();

    // x streams: p0 needs xf; p1 needs xi (upd) and xu (combine)
    const _Float16* pj = proj + (size_t)b * 768 + j;   // step stride 49152 f16
    float x0 = 0.f, x1 = 0.f, x2 = 0.f;
    if (p == 0) x0 = (float)pj[0];
    else if (p == 1) { x1 = (float)pj[256]; x2 = (float)pj[512]; }
    float* outp = out + (size_t)b * 256 + j;           // step stride 16384 f32
    float hlast = 0.f;

    for (int t = 0; t < 1024; ++t) {
        // prefetch next step's x (stays in flight across raw barriers)
        _Float16 r0 = (_Float16)0.f, r1 = (_Float16)0.f, r2 = (_Float16)0.f;
        if (t < 1023) {
            if (p == 0) r0 = pj[49152];
            else if (p == 1) { r1 = pj[49152 + 256]; r2 = pj[49152 + 512]; }
        }

        float hcur = (p < 2) ? sh_hf[j] : 0.f;   // only p0/p1 use it

        // phase A: partial gate dot over own h-half (uniform-address broadcast)
        float a0 = 0.f, a1 = 0.f, a2 = 0.f, a3 = 0.f;
        {
            const uint4* hh = (const uint4*)sh_h + half * 16;
#pragma unroll
            for (int m = 0; m < 16; m++) {
                UQ a; a.u = hh[m];
                a0 = FDOT2(wa[4 * m],     a.h[0], a0);
                a1 = FDOT2(wa[4 * m + 1], a.h[1], a1);
                a2 = FDOT2(wa[4 * m + 2], a.h[2], a2);
                a3 = FDOT2(wa[4 * m + 3], a.h[3], a3);
            }
        }
        sh_pa[tid] = (a0 + a1) + (a2 + a3);

        wg_barrier();   // B1: gate partials visible

        float upd = 0.f;
        if (p == 0) {
            float reset = 1.f / (1.f + __expf(-(x0 + sh_pa[j] + sh_pa[j + 256])));
            sh_rh[j] = (_Float16)(reset * hcur);
        } else if (p == 1) {
            upd = 1.f / (1.f + __expf(-(x1 + sh_pa[j + 512] + sh_pa[j + 768])));
        }

        wg_barrier();   // B2: rh visible (and pa reads done -> buffer reusable)

        // phase B: u-gate partial dot over own quarter of rh
        float u0 = 0.f, u1 = 0.f, u2 = 0.f, u3 = 0.f;
        {
            const uint4* rr = (const uint4*)sh_rh + p * 8;
#pragma unroll
            for (int m = 0; m < 8; m++) {
                UQ a; a.u = rr[m];
                u0 = FDOT2(wu[4 * m],     a.h[0], u0);
                u1 = FDOT2(wu[4 * m + 1], a.h[1], u1);
                u2 = FDOT2(wu[4 * m + 2], a.h[2], u2);
                u3 = FDOT2(wu[4 * m + 3], a.h[3], u3);
            }
        }
        sh_pa[tid] = (u0 + u1) + (u2 + u3);

        wg_barrier();   // B3: u partials visible

        if (p == 1) {
            float accu = (sh_pa[j] + sh_pa[j + 256]) + (sh_pa[j + 512] + sh_pa[j + 768]);
            float zc = x2 + accu;
            float e = __expf(2.f * zc);
            float cand = (e - 1.f) / (e + 1.f);            // tanh
            float hn = upd * hcur + (1.f - upd) * cand;
            sh_hf[j] = hn;
            sh_h[j] = (_Float16)hn;
            *outp = hn;                                     // fire-and-forget
            hlast = hn;
        }

        wg_barrier();   // B4: new h visible

        x0 = (float)r0; x1 = (float)r1; x2 = (float)r2;
        pj += 49152;
        outp += 16384;
    }

    if (p == 1) out[(size_t)16777216 + (size_t)b * 256 + j] = hlast;
}

extern "C" void kernel_launch(void* const* d_in, const int* in_sizes, int n_in,
                              void* d_out, int out_size, void* d_ws, size_t ws_size,
                              hipStream_t stream) {
    const float* X   = (const float*)d_in[0];
    const float* Wfx = (const float*)d_in[1];
    const float* Wfg = (const float*)d_in[2];
    const float* bfg = (const float*)d_in[3];
    const float* Wix = (const float*)d_in[4];
    const float* Wig = (const float*)d_in[5];
    const float* big = (const float*)d_in[6];
    const float* Wux = (const float*)d_in[7];
    const float* Wug = (const float*)d_in[8];
    const float* bug = (const float*)d_in[9];
    float* out = (float*)d_out;

    char* ws = (char*)d_ws;
    _Float16* proj = (_Float16*)ws;                          // 65536*768*2 = 100663296 B
    u16* WcatT = (u16*)(ws + 100663296);                     // 768*256*2   = 393216 B
    _Float16* WT = (_Float16*)(ws + 100663296 + 393216);     // 3*256*256*2 = 393216 B

    prep_wcat<<<768, 256, 0, stream>>>(Wfx, Wix, Wux, WcatT);
    prep_wrec<<<768, 256, 0, stream>>>(Wfg, bfg, Wig, big, Wug, bug, WT);
    proj_gemm<<<3072, 256, 0, stream>>>(X, WcatT, proj);
    gru_rec<<<64, 1024, 0, stream>>>(proj, WT, out);
}